// Round 7
// baseline (258.231 us; speedup 1.0000x reference)
//
#include <hip/hip_runtime.h>
#include <hip/hip_bf16.h>
#include <cstdint>

// Problem constants
#define SDIM 160
#define HDIM 768
#define HALF 384
#define ODIM 260
#define OPAD 272           // 17 * 16
// Workspace layout (bytes): pad@0(16) yb@16 Lb@245776 Rt@491536 W2b@737296
// (yb slot kept for offset stability; big path no longer writes it)
#define WS_NEED 1155088

typedef __attribute__((ext_vector_type(8))) short short8;
typedef __attribute__((ext_vector_type(4))) float floatx4;
typedef _Float16 half8 __attribute__((ext_vector_type(8)));

static __device__ __forceinline__ float bf2f(unsigned short u) {
    union { unsigned int i; float f; } v; v.i = ((unsigned int)u) << 16; return v.f;
}
static __device__ __forceinline__ unsigned short f2bf(float x) {
    __hip_bfloat16 h = __float2bfloat16(x);
    return *reinterpret_cast<unsigned short*>(&h);
}
static __device__ __forceinline__ unsigned short f2h(float x) {
    _Float16 h = (_Float16)x;
    return *reinterpret_cast<unsigned short*>(&h);
}

// ---------------------------------------------------------------------------
// Kernel A (R22): single prep+LR kernel, 64-thr blocks, no inter-block deps.
//   bid < 408   : W2b build -- W2 -> f16 [kg96][row272][8], row-fastest
//                 (coalesced stores; pad rows zeroed). Same math as old prep.
//   bid >= 408  : LR GEMM block (mt, sq) -- the proven lr3 shape, except:
//                 B-frag = in-register RoPE straight from y (no yb),
//                 A-frag = in-register f2bf straight from W1 (no W1b;
//                 R1-proven numerics, passed with identical absmax).
// Kills the separate prep launch (1 launch gap ~6us) and the yb/W1b
// round-trips. 1368 blocks = 5.3 waves/CU.
// ---------------------------------------------------------------------------
__global__ __launch_bounds__(64) void fused_a_kernel(
    const float* __restrict__ y, const float* __restrict__ W1,
    const float* __restrict__ b1, const float* __restrict__ W2,
    unsigned short* __restrict__ W2b,
    unsigned short* __restrict__ Lb, unsigned short* __restrict__ Rt) {
    int bid = blockIdx.x;
    int t = threadIdx.x;

    if (bid < 408) {
        int idx = bid * 64 + t;                 // [0, 26112)
        int kg = idx / OPAD, row = idx - kg * OPAD;   // row fastest
        unsigned short o8[8];
        if (row < ODIM) {
            float4 a = *reinterpret_cast<const float4*>(W2 + row * HDIM + kg * 8);
            float4 b = *reinterpret_cast<const float4*>(W2 + row * HDIM + kg * 8 + 4);
            o8[0] = f2h(a.x); o8[1] = f2h(a.y); o8[2] = f2h(a.z); o8[3] = f2h(a.w);
            o8[4] = f2h(b.x); o8[5] = f2h(b.y); o8[6] = f2h(b.z); o8[7] = f2h(b.w);
        } else {
            #pragma unroll
            for (int e = 0; e < 8; ++e) o8[e] = 0;
        }
        *reinterpret_cast<uint4*>(W2b + ((size_t)kg * OPAD + row) * 8) =
            *reinterpret_cast<uint4*>(o8);
        return;
    }

    // ---- LR block ----
    int bid2 = bid - 408;                       // [0, 960)
    int mt = bid2 % 96;                         // m-tile [0,96)
    int sq = bid2 / 96;                         // s-tile [0,10)
    int l16 = t & 15, qd = t >> 4;
    int s0 = sq * 16 + l16;
    int row = mt * 16 + l16;                    // W1b-equivalent row
    // block-uniform branch (mt<48 <=> L-half)
    const float* wrow = (row < 768) ? (W1 + (size_t)row * 1536)
                                    : (W1 + (size_t)(row - 768) * 1536 + 768);
    const float* yrow = y + (size_t)s0 * HDIM;
    float sf = (float)s0;

    floatx4 acc = (floatx4){0.0f, 0.0f, 0.0f, 0.0f};

    for (int ks = 0; ks < 24; ++ks) {
        int k = ks * 32 + qd * 8;
        int kg = ks * 4 + qd;
        // B-frag: RoPE(y[s0][k..k+8]) in-register (same formulas as old prep)
        float4 ya = *reinterpret_cast<const float4*>(yrow + k);
        float4 yb4 = *reinterpret_cast<const float4*>(yrow + k + 4);
        float yv[8] = {ya.x, ya.y, ya.z, ya.w, yb4.x, yb4.y, yb4.z, yb4.w};
        unsigned short b8[8];
        #pragma unroll
        for (int e = 0; e < 4; ++e) {
            int p = (k >> 1) + e;
            float invf = __expf(-(2.0f * (float)p / (float)HDIM) * 9.210340371976184f);
            float th = sf * invf;
            float c = cosf(th), sn = sinf(th);
            float y0 = yv[2 * e], y1 = yv[2 * e + 1];
            b8[2 * e]     = f2bf(y0 * c - y1 * sn);
            b8[2 * e + 1] = f2bf(y1 * c + y0 * sn);
        }
        // A-frag: W1 f32 -> bf16 in-register (R1-proven)
        float4 wa = *reinterpret_cast<const float4*>(wrow + kg * 8);
        float4 wb = *reinterpret_cast<const float4*>(wrow + kg * 8 + 4);
        unsigned short w8[8];
        w8[0] = f2bf(wa.x); w8[1] = f2bf(wa.y); w8[2] = f2bf(wa.z); w8[3] = f2bf(wa.w);
        w8[4] = f2bf(wb.x); w8[5] = f2bf(wb.y); w8[6] = f2bf(wb.z); w8[7] = f2bf(wb.w);
        union { uint4 u; short8 s; } au, bu;
        au.u = *reinterpret_cast<uint4*>(w8);
        bu.u = *reinterpret_cast<uint4*>(b8);
        acc = __builtin_amdgcn_mfma_f32_16x16x32_bf16(au.s, bu.s, acc, 0, 0, 0);
    }

    int o2 = mt * 16 + qd * 4;
    unsigned short out4[4];
    if (o2 < 768) {
        #pragma unroll
        for (int r = 0; r < 4; ++r) out4[r] = f2h(acc[r]);
        *reinterpret_cast<uint2*>(Lb + s0 * HDIM + o2) =
            *reinterpret_cast<uint2*>(out4);
    } else {
        int ob = o2 - 768;               // [0,768), aligned to 4
        #pragma unroll
        for (int r = 0; r < 4; ++r)
            out4[r] = f2h(acc[r] + b1[ob + r]);
        // Rt[kg=ob>>3][s][e=ob&7], 4 consecutive e -> uint2 store
        *reinterpret_cast<uint2*>(
            Rt + ((size_t)(ob >> 3) * SDIM + s0) * 8 + (ob & 7)) =
            *reinterpret_cast<uint2*>(out4);
    }
}

// ---------------------------------------------------------------------------
// Kernel B (R22): direct-global f16 pair-GEMM + 2-deep register pipeline.
// R6 post-mortem: direct-global main ran 42us with VGPR=44, MfmaUtil 9%,
// all pipes idle -> serial L2-latency chain; the `if (mtl < nmt)` guard on
// 5 of 7 loads per k-step blocked cross-iteration load hoisting.
// NOW: (a) branch-free inner loop -- always load & MFMA all 5 m-tiles
// (reads stay inside W2b's padded 17 tiles; acc[.][4] is garbage for mq<3
// and epilogue's nmt guard never stores it); (b) explicit 2-deep software
// pipeline: ISSUE(t+1) into the alternate named register set before
// consuming set t (#pragma unroll 2 keeps indices static, rule #20).
// Loads for t+1 overlap MFMA+VALU of t; compiler emits counted vmcnt.
// Grid (80,5,8) = 3200 single-wave blocks (~12.5/CU), no LDS, no barriers.
// HISTORY: r15 m-split REGR; R18 i-tile-4x REGR; R20 3-buf vmcnt REGR;
// R21 direct-global 42us (tied r14 while deleting LDS) -- this targets its
// exposed latency.
// ---------------------------------------------------------------------------
__global__ __launch_bounds__(64, 3) void main_kernel(
    const unsigned short* __restrict__ Lb, const unsigned short* __restrict__ Rt,
    const unsigned short* __restrict__ W2b,
    const float* __restrict__ b2, float* __restrict__ out) {
    int l = threadIdx.x & 63;
    int l16 = l & 15, qd = l >> 4;
    int w = blockIdx.z;              // 0..7
    int jh = w & 1;                  // j-half
    int mq = w >> 1;                 // m-quarter
    int mt0 = mq * 4;
    int nmt = (mq == 3) ? 5 : 4;     // epilogue-only now
    int i0 = blockIdx.x * 2;
    int j = blockIdx.y * 32 + jh * 16 + l16;

    floatx4 acc[2][5];
    #pragma unroll
    for (int c = 0; c < 2; ++c)
        #pragma unroll
        for (int mtl = 0; mtl < 5; ++mtl)
            acc[c][mtl] = (floatx4){0.0f, 0.0f, 0.0f, 0.0f};

    const unsigned short* Lrow0 = Lb + i0 * HDIM;
    const unsigned short* Lrow1 = Lb + (i0 + 1) * HDIM;
    const unsigned short* wbase = W2b + (size_t)l16 * 8;

    union U { uint4 u; half8 h; };
    U au[2][5], ru[2], lu[2][2];

    auto ISSUE = [&](int t, int b) {
        int kg = t * 4 + qd;                       // kg in [0,96)
        const unsigned short* wkg = wbase + (size_t)kg * (OPAD * 8);
        #pragma unroll
        for (int m = 0; m < 5; ++m)
            au[b][m].u = *reinterpret_cast<const uint4*>(
                wkg + (size_t)(mt0 + m) * 128);    // 16 rows * 8 elems
        ru[b].u = *reinterpret_cast<const uint4*>(
            Rt + ((size_t)kg * SDIM + j) * 8);
        int k = t * 32 + qd * 8;
        lu[b][0].u = *reinterpret_cast<const uint4*>(Lrow0 + k);
        lu[b][1].u = *reinterpret_cast<const uint4*>(Lrow1 + k);
    };

    ISSUE(0, 0);
    #pragma unroll 2
    for (int t = 0; t < 24; ++t) {
        int b = t & 1;
        if (t < 23) ISSUE(t + 1, b ^ 1);           // prefetch next k-step
        half8 bfrag[2];
        #pragma unroll
        for (int c = 0; c < 2; ++c) {
            half8 hv = lu[b][c].h + ru[b].h;       // v_pk_add_f16
            #pragma unroll
            for (int e = 0; e < 8; ++e)            // v_pk_max_f16
                hv[e] = hv[e] > (_Float16)0.0f ? hv[e] : (_Float16)0.0f;
            bfrag[c] = hv;
        }
        #pragma unroll
        for (int m = 0; m < 5; ++m) {              // branch-free: always 5
            acc[0][m] = __builtin_amdgcn_mfma_f32_16x16x32_f16(
                au[b][m].h, bfrag[0], acc[0][m], 0, 0, 0);
            acc[1][m] = __builtin_amdgcn_mfma_f32_16x16x32_f16(
                au[b][m].h, bfrag[1], acc[1][m], 0, 0, 0);
        }
    }

    #pragma unroll
    for (int c = 0; c < 2; ++c) {
        int i = i0 + c;
        #pragma unroll
        for (int mtl = 0; mtl < 5; ++mtl) {
            if (mtl < nmt) {                       // guard stays here
                int ob = (mt0 + mtl) * 16 + qd * 4;
                if (ob < ODIM) {
                    float4 bv = *reinterpret_cast<const float4*>(b2 + ob);
                    int rel = ob >> 2;
                    float4 v;
                    v.x = 1.0f / (1.0f + __expf(-(acc[c][mtl][0] + bv.x)));
                    v.y = 1.0f / (1.0f + __expf(-(acc[c][mtl][1] + bv.y)));
                    v.z = 1.0f / (1.0f + __expf(-(acc[c][mtl][2] + bv.z)));
                    v.w = 1.0f / (1.0f + __expf(-(acc[c][mtl][3] + bv.w)));
                    *reinterpret_cast<float4*>(
                        out + (((rel * SDIM) + i) * SDIM + j) * 4) = v;
                }
            }
        }
    }
}

__global__ void ws_too_small_kernel(float* out) { out[0] = 999.0f; }

extern "C" void kernel_launch(void* const* d_in, const int* in_sizes, int n_in,
                              void* d_out, int out_size, void* d_ws, size_t ws_size,
                              hipStream_t stream) {
    const float* y  = (const float*)d_in[0];
    // d_in[1] = event_idx : unused by the reference
    const float* W1 = (const float*)d_in[2];
    const float* b1 = (const float*)d_in[3];
    const float* W2 = (const float*)d_in[4];
    const float* b2 = (const float*)d_in[5];
    float* out = (float*)d_out;

    if (ws_size < (size_t)WS_NEED) {
        ws_too_small_kernel<<<dim3(1), dim3(1), 0, stream>>>(out);
        return;
    }

    unsigned short* yb  = (unsigned short*)((char*)d_ws + 16);    // legacy slot
    unsigned short* Lb  = yb + SDIM * HDIM;
    unsigned short* Rt  = Lb + SDIM * HDIM;                       // 96*160*8
    unsigned short* W2b = Rt + SDIM * HDIM;                       // 96*272*8

    fused_a_kernel<<<dim3(408 + 960), dim3(64), 0, stream>>>(
        y, W1, b1, W2, W2b, Lb, Rt);
    main_kernel<<<dim3(80, 5, 8), dim3(64), 0, stream>>>(Lb, Rt, W2b, b2, out);
}

// Round 9
// 123.553 us; speedup vs baseline: 2.0900x; 2.0900x over previous
//
#include <hip/hip_runtime.h>
#include <hip/hip_bf16.h>
#include <cstdint>

// Problem constants
#define SDIM 160
#define HDIM 768
#define HALF 384
#define ODIM 260
#define OPAD 272           // 17 * 16
#define CHUNK_BYTES 34816  // 8 kgroups * 272 rows * 16B (W2b chunk)
// Workspace layout (bytes): pad@0(16) yb@16 Lb@245776 Rt@491536 W2b@737296
//                           W1b@1155088 end@3514384
#define WS_SMALL 1155088
#define WS_BIG   3514384

typedef __attribute__((ext_vector_type(8))) short short8;
typedef __attribute__((ext_vector_type(4))) float floatx4;
typedef _Float16 half8 __attribute__((ext_vector_type(8)));

typedef const __attribute__((address_space(1))) unsigned char gl_u8;
typedef __attribute__((address_space(3))) unsigned char lds_u8;

static __device__ __forceinline__ float bf2f(unsigned short u) {
    union { unsigned int i; float f; } v; v.i = ((unsigned int)u) << 16; return v.f;
}
static __device__ __forceinline__ unsigned short f2bf(float x) {
    __hip_bfloat16 h = __float2bfloat16(x);
    return *reinterpret_cast<unsigned short*>(&h);
}
static __device__ __forceinline__ unsigned short f2h(float x) {
    _Float16 h = (_Float16)x;
    return *reinterpret_cast<unsigned short*>(&h);
}
static __device__ __forceinline__ float q(float x) { return bf2f(f2bf(x)); }

// ---------------------------------------------------------------------------
// Kernel 1 (R4-proven, UNCHANGED): RoPE(y) -> yb bf16; W2 -> W2b f16
// [kg96][row272][8]; (big path) W1 -> W1b bf16 [kg96][row1536][8].
// Row-fastest transpose mappings -> coalesced 16B stores.
// ---------------------------------------------------------------------------
__global__ __launch_bounds__(256) void prep_kernel(
    const float* __restrict__ y, const float* __restrict__ W1,
    const float* __restrict__ W2,
    unsigned short* __restrict__ yb, unsigned short* __restrict__ W2b,
    unsigned short* __restrict__ W1b, int do_w1b) {
    int bid = blockIdx.x;
    int t = threadIdx.x;
    if (bid < SDIM) {
        int s = bid;
        for (int p = t; p < HALF; p += 256) {
            float invf = __expf(-(2.0f * (float)p / (float)HDIM) * 9.210340371976184f);
            float th = (float)s * invf;
            float c = cosf(th), sn = sinf(th);
            float y0 = y[s * HDIM + 2 * p], y1 = y[s * HDIM + 2 * p + 1];
            yb[s * HDIM + 2 * p]     = f2bf(y0 * c - y1 * sn);
            yb[s * HDIM + 2 * p + 1] = f2bf(y1 * c + y0 * sn);
        }
    } else if (bid < SDIM + 102) {
        int idx = (bid - SDIM) * 256 + t;       // [0, 96*272)
        if (idx < 96 * OPAD) {
            int kg = idx / OPAD, row = idx - kg * OPAD;  // row fastest
            unsigned short o8[8];
            if (row < ODIM) {
                float4 a = *reinterpret_cast<const float4*>(W2 + row * HDIM + kg * 8);
                float4 b = *reinterpret_cast<const float4*>(W2 + row * HDIM + kg * 8 + 4);
                o8[0] = f2h(a.x); o8[1] = f2h(a.y); o8[2] = f2h(a.z); o8[3] = f2h(a.w);
                o8[4] = f2h(b.x); o8[5] = f2h(b.y); o8[6] = f2h(b.z); o8[7] = f2h(b.w);
            } else {
                #pragma unroll
                for (int e = 0; e < 8; ++e) o8[e] = 0;
            }
            *reinterpret_cast<uint4*>(W2b + ((size_t)kg * OPAD + row) * 8) =
                *reinterpret_cast<uint4*>(o8);
        }
    } else if (do_w1b) {
        int idx = (bid - SDIM - 102) * 256 + t; // [0, 96*1536)
        int kg = idx / 1536, row = idx - kg * 1536;      // row fastest
        const float* src = (row < 768) ? (W1 + row * 1536 + kg * 8)
                                       : (W1 + (row - 768) * 1536 + 768 + kg * 8);
        float4 a = *reinterpret_cast<const float4*>(src);
        float4 b = *reinterpret_cast<const float4*>(src + 4);
        unsigned short o8[8];
        o8[0] = f2bf(a.x); o8[1] = f2bf(a.y); o8[2] = f2bf(a.z); o8[3] = f2bf(a.w);
        o8[4] = f2bf(b.x); o8[5] = f2bf(b.y); o8[6] = f2bf(b.z); o8[7] = f2bf(b.w);
        *reinterpret_cast<uint4*>(W1b + ((size_t)kg * 1536 + row) * 8) =
            *reinterpret_cast<uint4*>(o8);
    }
}

// ---------------------------------------------------------------------------
// Kernel 2 (R4-proven, UNCHANGED): barrier-free L/R GEMM from W1b.
// Grid (96,10): one 16-row s-tile per wave, 960 waves (~3.75/CU).
// ---------------------------------------------------------------------------
__global__ __launch_bounds__(64, 2) void lr3_kernel(
    const unsigned short* __restrict__ yb, const unsigned short* __restrict__ W1b,
    const float* __restrict__ b1,
    unsigned short* __restrict__ Lb, unsigned short* __restrict__ Rt) {
    int l = threadIdx.x & 63;
    int l16 = l & 15, qd = l >> 4;
    int mt = blockIdx.x;                 // m-tile [0,96)
    int sq = blockIdx.y;                 // s-tile [0,10)
    int s0 = sq * 16 + l16;

    floatx4 acc = (floatx4){0.0f, 0.0f, 0.0f, 0.0f};

    const unsigned short* yrow0 = yb + s0 * HDIM;

    for (int ks = 0; ks < 24; ++ks) {
        int k = ks * 32 + qd * 8;
        int kg = ks * 4 + qd;
        union { uint4 u; short8 s; } bu0, au;
        bu0.u = *reinterpret_cast<const uint4*>(yrow0 + k);
        au.u = *reinterpret_cast<const uint4*>(
            W1b + ((size_t)kg * 1536 + mt * 16 + l16) * 8);
        acc = __builtin_amdgcn_mfma_f32_16x16x32_bf16(
            au.s, bu0.s, acc, 0, 0, 0);
    }

    int o2 = mt * 16 + qd * 4;
    int s_out = sq * 16 + l16;
    unsigned short out4[4];
    if (o2 < 768) {
        #pragma unroll
        for (int r = 0; r < 4; ++r) out4[r] = f2h(acc[r]);
        *reinterpret_cast<uint2*>(Lb + s_out * HDIM + o2) =
            *reinterpret_cast<uint2*>(out4);
    } else {
        int ob = o2 - 768;               // [0,768), aligned to 4
        #pragma unroll
        for (int r = 0; r < 4; ++r)
            out4[r] = f2h(acc[r] + b1[ob + r]);
        // Rt[kg=ob>>3][s][e=ob&7], 4 consecutive e -> uint2 store
        *reinterpret_cast<uint2*>(
            Rt + ((size_t)(ob >> 3) * SDIM + s_out) * 8 + (ob & 7)) =
            *reinterpret_cast<uint2*>(out4);
    }
}

// ---------------------------------------------------------------------------
// Kernel 3 (small-ws path only): pure-VALU L/R (f16; R transposed).
// ---------------------------------------------------------------------------
__global__ __launch_bounds__(256) void lr_fallback_kernel(
    const unsigned short* __restrict__ yb, const float* __restrict__ W1,
    const float* __restrict__ b1,
    unsigned short* __restrict__ Lb, unsigned short* __restrict__ Rt) {
    int idx = blockIdx.x * 256 + threadIdx.x;   // [0, 160*1536)
    int s = idx / 1536;
    int o2 = idx - s * 1536;
    const unsigned short* yrow = yb + s * HDIM;
    if (o2 < 768) {
        const float* wp = W1 + o2 * 1536;
        float a0 = 0.0f;
        for (int k = 0; k < HDIM; ++k) a0 += q(wp[k]) * bf2f(yrow[k]);
        Lb[s * HDIM + o2] = f2h(a0);
    } else {
        int ob = o2 - 768;
        const float* wp = W1 + ob * 1536 + 768;
        float a0 = 0.0f;
        for (int k = 0; k < HDIM; ++k) a0 += q(wp[k]) * bf2f(yrow[k]);
        Rt[((size_t)(ob >> 3) * SDIM + s) * 8 + (ob & 7)] = f2h(a0 + b1[ob]);
    }
}

// ---------------------------------------------------------------------------
// Kernel 4 (R24, resubmitted after R8 infra failure): r14 LDS pair-GEMM,
// i-pair SPLIT -> 1 i per block.
// WHY (R5/R6 isolated the binder): main is latency/TLP-bound -- R5 showed
// per-CU throughput scales with resident waves (1 block/CU = 26us/block;
// 2 blocks/CU = 19.4us/block; all pipes <10% busy either way). r14's grid
// (80,5)=400 fat blocks gave avg 12.5 waves/CU with a hard 2/1 imbalance.
// NOW: block = 8 waves x (1 i x 32 j), grid (160,5) = 800 blocks, LDS
// unchanged (2 x 34KB -> still 2 blocks/CU cap) -> ~16 waves/CU sustained
// on ALL CUs, finer-grained tail. Per-wave MFMA halves; h-build per (i,j,k)
// NOT duplicated (anti-r15: each wave builds 1 i, aggregate unchanged).
// Known costs (both proven non-binding): staging L2 traffic 2x (R3: not
// L2-BW-bound), au LDS reads 2x (R18: not LDS-read-bound).
// Per-(i,j,m) K-chain identical -> bit-identical output.
// HISTORY: r15 m-split REGR (dup h-build); R18 4i REGR (fewer waves);
// R20 3-buf REGR (1 blk/CU); R21 direct-global tied but fill-sensitive
// (L2 thrash in-situ); R22 reg-pipeline REGR (rule #20 scratch demotion).
// ---------------------------------------------------------------------------
__global__ __launch_bounds__(512) void main_kernel(
    const unsigned short* __restrict__ Lb, const unsigned short* __restrict__ Rt,
    const unsigned short* __restrict__ W2b,
    const float* __restrict__ b2, float* __restrict__ out) {
    __shared__ __align__(16) unsigned char lds[2 * CHUNK_BYTES];

    int w = threadIdx.x >> 6;        // 0..7
    int l = threadIdx.x & 63;
    int l16 = l & 15, qd = l >> 4;
    int jh = w & 1;                  // j-half
    int mq = w >> 1;                 // m-quarter
    int mt0 = mq * 4;
    int nmt = (mq == 3) ? 5 : 4;     // m-split 4/4/4/5 (17 tiles)
    int i = blockIdx.x;              // single i per block (was i0 = 2*bid)
    int j = blockIdx.y * 32 + jh * 16 + l16;

    floatx4 acc[5];
    #pragma unroll
    for (int mtl = 0; mtl < 5; ++mtl)
        acc[mtl] = (floatx4){0.0f, 0.0f, 0.0f, 0.0f};

    const unsigned short* Lrow = Lb + i * HDIM;
    const unsigned char* wsrc = reinterpret_cast<const unsigned char*>(W2b);

    // Stage chunk 0 into buffer 0. Wave w handles segments w, w+8, ... (<34).
    #pragma unroll
    for (int it = 0; it < 5; ++it) {
        int seg = w + it * 8;
        if (seg < 34) {
            __builtin_amdgcn_global_load_lds(
                (gl_u8*)(wsrc + seg * 1024 + l * 16),
                (lds_u8*)(lds + seg * 1024), 16, 0, 0);
        }
    }
    __syncthreads();

    for (int kc = 0; kc < 12; ++kc) {
        int buf = kc & 1;
        // Prefetch chunk kc+1 into the other buffer (async, overlaps compute).
        if (kc < 11) {
            const unsigned char* gsrc = wsrc + (kc + 1) * CHUNK_BYTES;
            unsigned char* ldst = lds + (1 - buf) * CHUNK_BYTES;
            #pragma unroll
            for (int it = 0; it < 5; ++it) {
                int seg = w + it * 8;
                if (seg < 34) {
                    __builtin_amdgcn_global_load_lds(
                        (gl_u8*)(gsrc + seg * 1024 + l * 16),
                        (lds_u8*)(ldst + seg * 1024), 16, 0, 0);
                }
            }
        }
        #pragma unroll
        for (int ks = 0; ks < 2; ++ks) {
            int k = kc * 64 + ks * 32 + qd * 8;
            int kg = kc * 8 + ks * 4 + qd;
            // R read: contiguous across lanes (Rt[kg][j][8])
            union { uint4 u; half8 h; } ru;
            ru.u = *reinterpret_cast<const uint4*>(
                Rt + ((size_t)kg * SDIM + j) * 8);
            union { uint4 u; half8 h; } lu;
            lu.u = *reinterpret_cast<const uint4*>(Lrow + k);
            half8 hv = lu.h + ru.h;              // v_pk_add_f16
            #pragma unroll
            for (int e = 0; e < 8; ++e)          // v_pk_max_f16
                hv[e] = hv[e] > (_Float16)0.0f ? hv[e] : (_Float16)0.0f;
            half8 bfrag = hv;

            int ldsbase = buf * CHUNK_BYTES + ((ks * 4 + qd) * OPAD + l16) * 16;
            #pragma unroll
            for (int mtl = 0; mtl < 5; ++mtl) {
                if (mtl < nmt) {
                    union { uint4 u; half8 h; } au;
                    au.u = *reinterpret_cast<const uint4*>(
                        lds + ldsbase + (mt0 + mtl) * 256);
                    acc[mtl] = __builtin_amdgcn_mfma_f32_16x16x32_f16(
                        au.h, bfrag, acc[mtl], 0, 0, 0);
                }
            }
        }
        __syncthreads();   // prefetch landed + reads of buf done
    }

    #pragma unroll
    for (int mtl = 0; mtl < 5; ++mtl) {
        if (mtl < nmt) {
            int ob = (mt0 + mtl) * 16 + qd * 4;
            if (ob < ODIM) {
                float4 bv = *reinterpret_cast<const float4*>(b2 + ob);
                int rel = ob >> 2;
                float4 v;
                v.x = 1.0f / (1.0f + __expf(-(acc[mtl][0] + bv.x)));
                v.y = 1.0f / (1.0f + __expf(-(acc[mtl][1] + bv.y)));
                v.z = 1.0f / (1.0f + __expf(-(acc[mtl][2] + bv.z)));
                v.w = 1.0f / (1.0f + __expf(-(acc[mtl][3] + bv.w)));
                *reinterpret_cast<float4*>(
                    out + (((rel * SDIM) + i) * SDIM + j) * 4) = v;
            }
        }
    }
}

__global__ void ws_too_small_kernel(float* out) { out[0] = 999.0f; }

extern "C" void kernel_launch(void* const* d_in, const int* in_sizes, int n_in,
                              void* d_out, int out_size, void* d_ws, size_t ws_size,
                              hipStream_t stream) {
    const float* y  = (const float*)d_in[0];
    // d_in[1] = event_idx : unused by the reference
    const float* W1 = (const float*)d_in[2];
    const float* b1 = (const float*)d_in[3];
    const float* W2 = (const float*)d_in[4];
    const float* b2 = (const float*)d_in[5];
    float* out = (float*)d_out;

    if (ws_size < (size_t)WS_SMALL) {
        ws_too_small_kernel<<<dim3(1), dim3(1), 0, stream>>>(out);
        return;
    }

    unsigned short* yb  = (unsigned short*)((char*)d_ws + 16);    // 160*768
    unsigned short* Lb  = yb + SDIM * HDIM;
    unsigned short* Rt  = Lb + SDIM * HDIM;                       // 96*160*8
    unsigned short* W2b = Rt + SDIM * HDIM;                       // 96*272*8
    unsigned short* W1b = W2b + 96 * OPAD * 8;                    // 96*1536*8

    if (ws_size >= (size_t)WS_BIG) {
        prep_kernel<<<dim3(SDIM + 102 + 576), dim3(256), 0, stream>>>(
            y, W1, W2, yb, W2b, W1b, 1);
        lr3_kernel<<<dim3(96, 10), dim3(64), 0, stream>>>(yb, W1b, b1, Lb, Rt);
        main_kernel<<<dim3(160, 5), dim3(512), 0, stream>>>(Lb, Rt, W2b, b2, out);
    } else {
        prep_kernel<<<dim3(SDIM + 102), dim3(256), 0, stream>>>(
            y, W1, W2, yb, W2b, W1b, 0);
        lr_fallback_kernel<<<dim3(960), dim3(256), 0, stream>>>(yb, W1, b1, Lb, Rt);
        main_kernel<<<dim3(160, 5), dim3(512), 0, stream>>>(Lb, Rt, W2b, b2, out);
    }
}

// Round 10
// 104.419 us; speedup vs baseline: 2.4730x; 1.1832x over previous
//
#include <hip/hip_runtime.h>
#include <hip/hip_bf16.h>
#include <cstdint>

// Problem constants
#define SDIM 160
#define HDIM 768
#define HALF 384
#define ODIM 260
#define OPAD 272           // 17 * 16
#define CHUNK_BYTES 34816  // 8 kgroups * 272 rows * 16B (W2b chunk)
#define RT_CHUNK 4096      // 8 kgroups * 32 j * 16B (Rt chunk slab)
#define BUF_STRIDE 38912   // CHUNK_BYTES + RT_CHUNK
#define LB_OFF 77824       // 2 * BUF_STRIDE
// total LDS = 77824 + 3072 = 80896 <= 81920 (2 blocks/CU)
// Workspace layout (bytes): pad@0(16) yb@16 Lb@245776 Rt@491536 W2b@737296
//                           W1b@1155088 end@3514384
#define WS_SMALL 1155088
#define WS_BIG   3514384

typedef __attribute__((ext_vector_type(8))) short short8;
typedef __attribute__((ext_vector_type(4))) float floatx4;
typedef _Float16 half8 __attribute__((ext_vector_type(8)));

typedef const __attribute__((address_space(1))) unsigned char gl_u8;
typedef __attribute__((address_space(3))) unsigned char lds_u8;

static __device__ __forceinline__ float bf2f(unsigned short u) {
    union { unsigned int i; float f; } v; v.i = ((unsigned int)u) << 16; return v.f;
}
static __device__ __forceinline__ unsigned short f2bf(float x) {
    __hip_bfloat16 h = __float2bfloat16(x);
    return *reinterpret_cast<unsigned short*>(&h);
}
static __device__ __forceinline__ unsigned short f2h(float x) {
    _Float16 h = (_Float16)x;
    return *reinterpret_cast<unsigned short*>(&h);
}
static __device__ __forceinline__ float q(float x) { return bf2f(f2bf(x)); }

// ---------------------------------------------------------------------------
// Kernel 1 (R4-proven, UNCHANGED): RoPE(y) -> yb bf16; W2 -> W2b f16
// [kg96][row272][8]; (big path) W1 -> W1b bf16 [kg96][row1536][8].
// ---------------------------------------------------------------------------
__global__ __launch_bounds__(256) void prep_kernel(
    const float* __restrict__ y, const float* __restrict__ W1,
    const float* __restrict__ W2,
    unsigned short* __restrict__ yb, unsigned short* __restrict__ W2b,
    unsigned short* __restrict__ W1b, int do_w1b) {
    int bid = blockIdx.x;
    int t = threadIdx.x;
    if (bid < SDIM) {
        int s = bid;
        for (int p = t; p < HALF; p += 256) {
            float invf = __expf(-(2.0f * (float)p / (float)HDIM) * 9.210340371976184f);
            float th = (float)s * invf;
            float c = cosf(th), sn = sinf(th);
            float y0 = y[s * HDIM + 2 * p], y1 = y[s * HDIM + 2 * p + 1];
            yb[s * HDIM + 2 * p]     = f2bf(y0 * c - y1 * sn);
            yb[s * HDIM + 2 * p + 1] = f2bf(y1 * c + y0 * sn);
        }
    } else if (bid < SDIM + 102) {
        int idx = (bid - SDIM) * 256 + t;       // [0, 96*272)
        if (idx < 96 * OPAD) {
            int kg = idx / OPAD, row = idx - kg * OPAD;  // row fastest
            unsigned short o8[8];
            if (row < ODIM) {
                float4 a = *reinterpret_cast<const float4*>(W2 + row * HDIM + kg * 8);
                float4 b = *reinterpret_cast<const float4*>(W2 + row * HDIM + kg * 8 + 4);
                o8[0] = f2h(a.x); o8[1] = f2h(a.y); o8[2] = f2h(a.z); o8[3] = f2h(a.w);
                o8[4] = f2h(b.x); o8[5] = f2h(b.y); o8[6] = f2h(b.z); o8[7] = f2h(b.w);
            } else {
                #pragma unroll
                for (int e = 0; e < 8; ++e) o8[e] = 0;
            }
            *reinterpret_cast<uint4*>(W2b + ((size_t)kg * OPAD + row) * 8) =
                *reinterpret_cast<uint4*>(o8);
        }
    } else if (do_w1b) {
        int idx = (bid - SDIM - 102) * 256 + t; // [0, 96*1536)
        int kg = idx / 1536, row = idx - kg * 1536;      // row fastest
        const float* src = (row < 768) ? (W1 + row * 1536 + kg * 8)
                                       : (W1 + (row - 768) * 1536 + 768 + kg * 8);
        float4 a = *reinterpret_cast<const float4*>(src);
        float4 b = *reinterpret_cast<const float4*>(src + 4);
        unsigned short o8[8];
        o8[0] = f2bf(a.x); o8[1] = f2bf(a.y); o8[2] = f2bf(a.z); o8[3] = f2bf(a.w);
        o8[4] = f2bf(b.x); o8[5] = f2bf(b.y); o8[6] = f2bf(b.z); o8[7] = f2bf(b.w);
        *reinterpret_cast<uint4*>(W1b + ((size_t)kg * 1536 + row) * 8) =
            *reinterpret_cast<uint4*>(o8);
    }
}

// ---------------------------------------------------------------------------
// Kernel 2 (R4-proven, UNCHANGED): barrier-free L/R GEMM from W1b.
// Grid (96,10): one 16-row s-tile per wave, 960 waves (~3.75/CU).
// ---------------------------------------------------------------------------
__global__ __launch_bounds__(64, 2) void lr3_kernel(
    const unsigned short* __restrict__ yb, const unsigned short* __restrict__ W1b,
    const float* __restrict__ b1,
    unsigned short* __restrict__ Lb, unsigned short* __restrict__ Rt) {
    int l = threadIdx.x & 63;
    int l16 = l & 15, qd = l >> 4;
    int mt = blockIdx.x;                 // m-tile [0,96)
    int sq = blockIdx.y;                 // s-tile [0,10)
    int s0 = sq * 16 + l16;

    floatx4 acc = (floatx4){0.0f, 0.0f, 0.0f, 0.0f};

    const unsigned short* yrow0 = yb + s0 * HDIM;

    for (int ks = 0; ks < 24; ++ks) {
        int k = ks * 32 + qd * 8;
        int kg = ks * 4 + qd;
        union { uint4 u; short8 s; } bu0, au;
        bu0.u = *reinterpret_cast<const uint4*>(yrow0 + k);
        au.u = *reinterpret_cast<const uint4*>(
            W1b + ((size_t)kg * 1536 + mt * 16 + l16) * 8);
        acc = __builtin_amdgcn_mfma_f32_16x16x32_bf16(
            au.s, bu0.s, acc, 0, 0, 0);
    }

    int o2 = mt * 16 + qd * 4;
    int s_out = sq * 16 + l16;
    unsigned short out4[4];
    if (o2 < 768) {
        #pragma unroll
        for (int r = 0; r < 4; ++r) out4[r] = f2h(acc[r]);
        *reinterpret_cast<uint2*>(Lb + s_out * HDIM + o2) =
            *reinterpret_cast<uint2*>(out4);
    } else {
        int ob = o2 - 768;               // [0,768), aligned to 4
        #pragma unroll
        for (int r = 0; r < 4; ++r)
            out4[r] = f2h(acc[r] + b1[ob + r]);
        // Rt[kg=ob>>3][s][e=ob&7], 4 consecutive e -> uint2 store
        *reinterpret_cast<uint2*>(
            Rt + ((size_t)(ob >> 3) * SDIM + s_out) * 8 + (ob & 7)) =
            *reinterpret_cast<uint2*>(out4);
    }
}

// ---------------------------------------------------------------------------
// Kernel 3 (small-ws path only): pure-VALU L/R (f16; R transposed).
// ---------------------------------------------------------------------------
__global__ __launch_bounds__(256) void lr_fallback_kernel(
    const unsigned short* __restrict__ yb, const float* __restrict__ W1,
    const float* __restrict__ b1,
    unsigned short* __restrict__ Lb, unsigned short* __restrict__ Rt) {
    int idx = blockIdx.x * 256 + threadIdx.x;   // [0, 160*1536)
    int s = idx / 1536;
    int o2 = idx - s * 1536;
    const unsigned short* yrow = yb + s * HDIM;
    if (o2 < 768) {
        const float* wp = W1 + o2 * 1536;
        float a0 = 0.0f;
        for (int k = 0; k < HDIM; ++k) a0 += q(wp[k]) * bf2f(yrow[k]);
        Lb[s * HDIM + o2] = f2h(a0);
    } else {
        int ob = o2 - 768;
        const float* wp = W1 + ob * 1536 + 768;
        float a0 = 0.0f;
        for (int k = 0; k < HDIM; ++k) a0 += q(wp[k]) * bf2f(yrow[k]);
        Rt[((size_t)(ob >> 3) * SDIM + s) * 8 + (ob & 7)] = f2h(a0 + b1[ob]);
    }
}

// ---------------------------------------------------------------------------
// Kernel 4 (R26): r14 pair-GEMM + FULL LDS STAGING (Rt chunk slab + Lb rows).
// WHY (R5/R6/R9 triangulation): main is ~39-53us across ALL structures with
// every pipe <25% busy; occupancy changes (R9: +70% waves) and LDS->global
// swaps (R6) don't move it. The only fitting model: per-CU VMEM-instruction
// throughput (~40cy per 1KB/16-line vector load). r14 issues 984 VMEM
// instrs/block of which 576 are DUPLICATES: ru re-read by all 4 mq-waves,
// lu by all 8 waves. NOW: Rt's per-chunk slab (8kg x 32j x 16B = 4KB) is
// double-buffered NEXT TO the W2b chunk (one fused STAGE, 38 segs), Lb's 2
// rows (3KB) staged once; in-loop ru/lu become ds_reads (LDS pipe idle;
// ru pattern = same bank layout as proven au reads -> 0 conflicts; lu is a
// 16-lane broadcast). VMEM/block: 984 -> 459. LDS 80896B <= 81920 keeps
// 2 blocks/CU. Same bytes, same compute chains, same barrier structure ->
// bit-identical output.
// HISTORY: r15 m-split REGR; R18 4i REGR; R20 3-buf REGR (residency);
// R21/R6 direct-global ~42; R22 reg-pipe REGR (rule #20); R24/R9 i-split
// REGR (43.1; falsified TLP theory).
// ---------------------------------------------------------------------------
__global__ __launch_bounds__(512) void main_kernel(
    const unsigned short* __restrict__ Lb, const unsigned short* __restrict__ Rt,
    const unsigned short* __restrict__ W2b,
    const float* __restrict__ b2, float* __restrict__ out) {
    __shared__ __align__(16) unsigned char lds[2 * BUF_STRIDE + 3072];

    int w = threadIdx.x >> 6;        // 0..7
    int l = threadIdx.x & 63;
    int l16 = l & 15, qd = l >> 4;
    int jh = w & 1;                  // j-half
    int mq = w >> 1;                 // m-quarter
    int mt0 = mq * 4;
    int nmt = (mq == 3) ? 5 : 4;     // m-split 4/4/4/5 (17 tiles)
    int i0 = blockIdx.x * 2;
    int j0 = blockIdx.y * 32;
    int j = j0 + jh * 16 + l16;

    floatx4 acc[2][5];
    #pragma unroll
    for (int c = 0; c < 2; ++c)
        #pragma unroll
        for (int mtl = 0; mtl < 5; ++mtl)
            acc[c][mtl] = (floatx4){0.0f, 0.0f, 0.0f, 0.0f};

    const unsigned char* wsrc = reinterpret_cast<const unsigned char*>(W2b);
    const unsigned char* rtsrc = reinterpret_cast<const unsigned char*>(Rt);
    const unsigned char* lbsrc = reinterpret_cast<const unsigned char*>(Lb);

    // Fused STAGE of chunk ch into buffer b: 34 W2b segs + 4 Rt segs.
    // W2b seg: linear 1KB. Rt seg s2 (0..3): lanes gather 2 kg-rows of 32 j
    // (per-lane global addr; LDS dest lane-linear: 34816 + s2*1024 + l*16).
    auto STAGE = [&](int ch, int b) {
        unsigned char* lbuf = lds + b * BUF_STRIDE;
        #pragma unroll
        for (int it = 0; it < 5; ++it) {
            int seg = w + it * 8;
            if (seg < 34) {
                __builtin_amdgcn_global_load_lds(
                    (gl_u8*)(wsrc + (size_t)ch * CHUNK_BYTES + seg * 1024 + l * 16),
                    (lds_u8*)(lbuf + seg * 1024), 16, 0, 0);
            } else if (seg < 38) {
                int s2 = seg - 34;                 // 0..3
                int kgl = s2 * 2 + (l >> 5);       // kg within chunk, 0..7
                int jj = l & 31;
                __builtin_amdgcn_global_load_lds(
                    (gl_u8*)(rtsrc + (((size_t)(ch * 8 + kgl) * SDIM) + j0 + jj) * 16),
                    (lds_u8*)(lbuf + CHUNK_BYTES + s2 * 1024), 16, 0, 0);
            }
        }
    };

    // Lb rows (2 x 1536B = 3 segs), staged once by waves 0..2.
    if (w < 3) {
        int bofs = w * 1024 + l * 16;              // [0, 3072)
        int row = bofs >= 1536 ? 1 : 0;
        int off = bofs - row * 1536;
        __builtin_amdgcn_global_load_lds(
            (gl_u8*)(lbsrc + ((size_t)(i0 + row) * HDIM) * 2 + off),
            (lds_u8*)(lds + LB_OFF + w * 1024), 16, 0, 0);
    }
    STAGE(0, 0);
    __syncthreads();

    for (int kc = 0; kc < 12; ++kc) {
        int buf = kc & 1;
        if (kc < 11) STAGE(kc + 1, 1 - buf);   // async prefetch, overlaps compute
        #pragma unroll
        for (int ks = 0; ks < 2; ++ks) {
            int kgl = ks * 4 + qd;             // kg within chunk
            // ru from LDS slab: [kgl][j-j0][8] f16
            half8 rh = *reinterpret_cast<const half8*>(
                lds + buf * BUF_STRIDE + CHUNK_BYTES +
                (kgl * 32 + jh * 16 + l16) * 16);
            int kb = (kc * 64 + ks * 32 + qd * 8) * 2;  // byte offset in Lb row
            half8 bfrag[2];
            #pragma unroll
            for (int c = 0; c < 2; ++c) {
                half8 lh = *reinterpret_cast<const half8*>(
                    lds + LB_OFF + c * 1536 + kb);      // 16-lane broadcast
                half8 hv = lh + rh;                     // v_pk_add_f16
                #pragma unroll
                for (int e = 0; e < 8; ++e)             // v_pk_max_f16
                    hv[e] = hv[e] > (_Float16)0.0f ? hv[e] : (_Float16)0.0f;
                bfrag[c] = hv;
            }
            int ldsbase = buf * BUF_STRIDE + (kgl * OPAD + l16) * 16;
            #pragma unroll
            for (int mtl = 0; mtl < 5; ++mtl) {
                if (mtl < nmt) {
                    half8 ah = *reinterpret_cast<const half8*>(
                        lds + ldsbase + (mt0 + mtl) * 256);
                    acc[0][mtl] = __builtin_amdgcn_mfma_f32_16x16x32_f16(
                        ah, bfrag[0], acc[0][mtl], 0, 0, 0);
                    acc[1][mtl] = __builtin_amdgcn_mfma_f32_16x16x32_f16(
                        ah, bfrag[1], acc[1][mtl], 0, 0, 0);
                }
            }
        }
        __syncthreads();   // prefetch landed + reads of buf done
    }

    #pragma unroll
    for (int c = 0; c < 2; ++c) {
        int i = i0 + c;
        #pragma unroll
        for (int mtl = 0; mtl < 5; ++mtl) {
            if (mtl < nmt) {
                int ob = (mt0 + mtl) * 16 + qd * 4;
                if (ob < ODIM) {
                    float4 bv = *reinterpret_cast<const float4*>(b2 + ob);
                    int rel = ob >> 2;
                    float4 v;
                    v.x = 1.0f / (1.0f + __expf(-(acc[c][mtl][0] + bv.x)));
                    v.y = 1.0f / (1.0f + __expf(-(acc[c][mtl][1] + bv.y)));
                    v.z = 1.0f / (1.0f + __expf(-(acc[c][mtl][2] + bv.z)));
                    v.w = 1.0f / (1.0f + __expf(-(acc[c][mtl][3] + bv.w)));
                    *reinterpret_cast<float4*>(
                        out + (((rel * SDIM) + i) * SDIM + j) * 4) = v;
                }
            }
        }
    }
}

__global__ void ws_too_small_kernel(float* out) { out[0] = 999.0f; }

extern "C" void kernel_launch(void* const* d_in, const int* in_sizes, int n_in,
                              void* d_out, int out_size, void* d_ws, size_t ws_size,
                              hipStream_t stream) {
    const float* y  = (const float*)d_in[0];
    // d_in[1] = event_idx : unused by the reference
    const float* W1 = (const float*)d_in[2];
    const float* b1 = (const float*)d_in[3];
    const float* W2 = (const float*)d_in[4];
    const float* b2 = (const float*)d_in[5];
    float* out = (float*)d_out;

    if (ws_size < (size_t)WS_SMALL) {
        ws_too_small_kernel<<<dim3(1), dim3(1), 0, stream>>>(out);
        return;
    }

    unsigned short* yb  = (unsigned short*)((char*)d_ws + 16);    // 160*768
    unsigned short* Lb  = yb + SDIM * HDIM;
    unsigned short* Rt  = Lb + SDIM * HDIM;                       // 96*160*8
    unsigned short* W2b = Rt + SDIM * HDIM;                       // 96*272*8
    unsigned short* W1b = W2b + 96 * OPAD * 8;                    // 96*1536*8

    if (ws_size >= (size_t)WS_BIG) {
        prep_kernel<<<dim3(SDIM + 102 + 576), dim3(256), 0, stream>>>(
            y, W1, W2, yb, W2b, W1b, 1);
        lr3_kernel<<<dim3(96, 10), dim3(64), 0, stream>>>(yb, W1b, b1, Lb, Rt);
        main_kernel<<<dim3(80, 5), dim3(512), 0, stream>>>(Lb, Rt, W2b, b2, out);
    } else {
        prep_kernel<<<dim3(SDIM + 102), dim3(256), 0, stream>>>(
            y, W1, W2, yb, W2b, W1b, 0);
        lr_fallback_kernel<<<dim3(960), dim3(256), 0, stream>>>(yb, W1, b1, Lb, Rt);
        main_kernel<<<dim3(80, 5), dim3(512), 0, stream>>>(Lb, Rt, W2b, b2, out);
    }
}